// Round 6
// baseline (353.373 us; speedup 1.0000x reference)
//
#include <hip/hip_runtime.h>
#include <hip/hip_bf16.h>
#include <stdint.h>

typedef short short8 __attribute__((ext_vector_type(8)));
typedef short short4v __attribute__((ext_vector_type(4)));
typedef float f32x4 __attribute__((ext_vector_type(4)));

static __device__ __forceinline__ short f2bf(float f) {
  union { float f; uint32_t u; } v; v.f = f;
  uint32_t r = (v.u + 0x7fffu + ((v.u >> 16) & 1u)) >> 16;
  return (short)(uint16_t)r;
}
static __device__ __forceinline__ float bf2f(short h) {
  union { uint32_t u; float f; } v; v.u = ((uint32_t)(uint16_t)h) << 16;
  return v.f;
}

#define MFMA(a, b, c) __builtin_amdgcn_mfma_f32_16x16x32_bf16((a), (b), (c), 0, 0, 0)

static __device__ __forceinline__ void gload16(const short* g, short* l) {
  __builtin_amdgcn_global_load_lds(
      (const __attribute__((address_space(1))) void*)g,
      (__attribute__((address_space(3))) void*)l, 16, 0, 0);
}

// ===========================================================================
// 256x256 GEMM core, BK=32, 4-slot LDS ring (4 x 32KB = 128 KiB).
// 512 threads = 8 waves (2 wm x 4 wn), wave tile 128x64, acc[8][4].
// Stage tile t+3 while computing tile t (prefetch distance 3 => ~6 phases of
// latency cover).  Counted s_waitcnt: vmcnt(8) in steady state (retires only
// tile t+1; t+2,t+3 stay in flight) — never drains to 0 in-loop (T4).
// Per K-tile: 2 phases x {ds_read (4 A b128 [+4 B at p0]) | issue 2 gload_lds
// | barrier | lgkmcnt(0)+sched_barrier | setprio(1) 16 MFMA setprio(0) |
// [p1: counted vmcnt] | barrier}.
// LDS swizzle: 16B chunk c of row r at c ^ ((r>>1)&3) — measured 0 bank
// conflicts (r3).  Staging pre-swizzles the GLOBAL source; LDS dest linear.
// acc C/D layout: col = lane&15, row = (lane>>4)*4 + i.
// ===========================================================================
static __device__ __forceinline__ void gemm256_ring(
    const short* __restrict__ Ag, int lda,
    const short* __restrict__ Bg, int ldb, int kext,
    short* lds, int t, f32x4 (&acc)[8][4])
{
  const int w = t >> 6, lane = t & 63;
  const int lr = lane & 15, lk = lane >> 4;
  const int wm = w >> 2, wn = w & 3;
  const int nk = kext >> 5;   // BK = 32

  // staging source addresses (2 gloads per matrix per tile per thread)
  const int i0 = t, i1 = 512 + t;
  const int r0 = i0 >> 2, c0 = (i0 & 3) ^ ((r0 >> 1) & 3);
  const int r1 = i1 >> 2, c1 = (i1 & 3) ^ ((r1 >> 1) & 3);
  const short* a0 = Ag + (size_t)r0 * lda + c0 * 8;
  const short* a1 = Ag + (size_t)r1 * lda + c1 * 8;
  const short* b0 = Bg + (size_t)r0 * ldb + c0 * 8;
  const short* b1 = Bg + (size_t)r1 * ldb + c1 * 8;
  // ds_read chunk offset (row-independent: (rl>>1)&3 == (lr>>1)&3 here)
  const int chq = (lk ^ ((lr >> 1) & 3)) * 8;

  // prologue: stage tiles 0,1,2 (order per tile: a0,a1,b0,b1 = 4 vm ops)
#pragma unroll
  for (int p = 0; p < 3; ++p) {
    short* slot = lds + p * 16384;
    gload16(a0 + p * 32, slot + w * 512);
    gload16(a1 + p * 32, slot + 4096 + w * 512);
    gload16(b0 + p * 32, slot + 8192 + w * 512);
    gload16(b1 + p * 32, slot + 12288 + w * 512);
  }
  asm volatile("s_waitcnt vmcnt(8)" ::: "memory");   // tile 0 landed
  __builtin_amdgcn_s_barrier();

  for (int tt = 0; tt < nk; ++tt) {
    short* slot  = lds + (tt & 3) * 16384;
    short* nslot = lds + ((tt + 3) & 3) * 16384;
    const int kk = (tt + 3) << 5;
    const bool st = (tt + 3) < nk;
    short8 bfr[4];

    // ---- phase 0: A frags 0-3 + all B; issue next A ----
    short8 af[4];
#pragma unroll
    for (int mt = 0; mt < 4; ++mt) {
      int rl = wm * 128 + mt * 16 + lr;
      af[mt] = *(const short8*)&slot[rl * 32 + chq];
    }
#pragma unroll
    for (int nt = 0; nt < 4; ++nt) {
      int rl = wn * 64 + nt * 16 + lr;
      bfr[nt] = *(const short8*)&slot[8192 + rl * 32 + chq];
    }
    if (st) {
      gload16(a0 + kk, nslot + w * 512);
      gload16(a1 + kk, nslot + 4096 + w * 512);
    }
    __builtin_amdgcn_s_barrier();
    asm volatile("s_waitcnt lgkmcnt(0)" ::: "memory");
    __builtin_amdgcn_sched_barrier(0);
    __builtin_amdgcn_s_setprio(1);
#pragma unroll
    for (int mt = 0; mt < 4; ++mt)
#pragma unroll
      for (int nt = 0; nt < 4; ++nt)
        acc[mt][nt] = MFMA(af[mt], bfr[nt], acc[mt][nt]);
    __builtin_amdgcn_s_setprio(0);
    __builtin_amdgcn_s_barrier();

    // ---- phase 1: A frags 4-7; issue next B; counted vmcnt ----
#pragma unroll
    for (int mt = 0; mt < 4; ++mt) {
      int rl = wm * 128 + (4 + mt) * 16 + lr;
      af[mt] = *(const short8*)&slot[rl * 32 + chq];
    }
    if (st) {
      gload16(b0 + kk, nslot + 8192 + w * 512);
      gload16(b1 + kk, nslot + 12288 + w * 512);
    }
    __builtin_amdgcn_s_barrier();
    asm volatile("s_waitcnt lgkmcnt(0)" ::: "memory");
    __builtin_amdgcn_sched_barrier(0);
    __builtin_amdgcn_s_setprio(1);
#pragma unroll
    for (int mt = 0; mt < 4; ++mt)
#pragma unroll
      for (int nt = 0; nt < 4; ++nt)
        acc[4 + mt][nt] = MFMA(af[mt], bfr[nt], acc[4 + mt][nt]);
    __builtin_amdgcn_s_setprio(0);
    const int rem = nk - 1 - tt;
    if (rem >= 3)      { asm volatile("s_waitcnt vmcnt(8)" ::: "memory"); }
    else if (rem == 2) { asm volatile("s_waitcnt vmcnt(4)" ::: "memory"); }
    else if (rem == 1) { asm volatile("s_waitcnt vmcnt(0)" ::: "memory"); }
    __builtin_amdgcn_s_barrier();
  }
}

// ===========================================================================
// 128x128 2-barrier GEMM core (r3, proven) — for PV (variable K, good packing).
// ===========================================================================
static __device__ __forceinline__ void gemm_tile128(
    const short* __restrict__ Ag, int lda,
    const short* __restrict__ Bg, int ldb, int kext,
    short* Alds, short* Blds, int w, int lane, f32x4 (&acc)[4][4])
{
  const int wr = (w >> 1) * 64, wc = (w & 1) * 64;
  const int lr = lane & 15, lk = lane >> 4;

  const int c0 = w * 128 + lane;
  const int c1 = c0 + 64;
  const int r0 = c0 >> 2, cg0 = (c0 & 3) ^ ((r0 >> 1) & 3);
  const int r1 = c1 >> 2, cg1 = (c1 & 3) ^ ((r1 >> 1) & 3);
  const short* a0 = Ag + (size_t)r0 * lda + cg0 * 8;
  const short* a1 = Ag + (size_t)r1 * lda + cg1 * 8;
  const short* b0 = Bg + (size_t)r0 * ldb + cg0 * 8;
  const short* b1 = Bg + (size_t)r1 * ldb + cg1 * 8;
  short* la0 = Alds + w * 1024;
  short* la1 = la0 + 512;
  short* lb0 = Blds + w * 1024;
  short* lb1 = lb0 + 512;

  int ra[4], rb[4];
#pragma unroll
  for (int mt = 0; mt < 4; ++mt) {
    int rl = wr + mt * 16 + lr;
    ra[mt] = rl * 32 + (lk ^ ((rl >> 1) & 3)) * 8;
  }
#pragma unroll
  for (int nt = 0; nt < 4; ++nt) {
    int rl = wc + nt * 16 + lr;
    rb[nt] = rl * 32 + (lk ^ ((rl >> 1) & 3)) * 8;
  }

  for (int kk = 0; kk < kext; kk += 32) {
    if (kk) __syncthreads();
    gload16(a0 + kk, la0);
    gload16(a1 + kk, la1);
    gload16(b0 + kk, lb0);
    gload16(b1 + kk, lb1);
    __syncthreads();
    short8 af[4], bfr[4];
#pragma unroll
    for (int mt = 0; mt < 4; ++mt) af[mt] = *(const short8*)&Alds[ra[mt]];
#pragma unroll
    for (int nt = 0; nt < 4; ++nt) bfr[nt] = *(const short8*)&Blds[rb[nt]];
#pragma unroll
    for (int mt = 0; mt < 4; ++mt)
#pragma unroll
      for (int nt = 0; nt < 4; ++nt)
        acc[mt][nt] = MFMA(af[mt], bfr[nt], acc[mt][nt]);
  }
}

// ---------------------------------------------------------------------------
// x f32 -> bf16
// ---------------------------------------------------------------------------
__global__ __launch_bounds__(256)
void cvt_x(const float* __restrict__ x, short* __restrict__ xb) {
  size_t i = (size_t)blockIdx.x * 256 + threadIdx.x;
  f32x4 a = *(const f32x4*)(x + i * 8);
  f32x4 b = *(const f32x4*)(x + i * 8 + 4);
  short8 h = { f2bf(a.x), f2bf(a.y), f2bf(a.z), f2bf(a.w),
               f2bf(b.x), f2bf(b.y), f2bf(b.z), f2bf(b.w) };
  *(short8*)(xb + i * 8) = h;
}

// ---------------------------------------------------------------------------
// W f32 [din][dout] -> Wt bf16 [z][dout][din]  (z=0 folds the 1/32 scale)
// ---------------------------------------------------------------------------
__global__ __launch_bounds__(256)
void cvt_w(const float* __restrict__ Wq, const float* __restrict__ Wk,
           const float* __restrict__ Wv, short* __restrict__ wt) {
  __shared__ short Tl[128][136];
  const int z = blockIdx.z;
  const float* W = (z == 0) ? Wq : (z == 1) ? Wk : Wv;
  const float scale = (z == 0) ? 0.03125f : 1.0f;
  const int c0 = blockIdx.x * 128, r0 = blockIdx.y * 128;
  const int t = threadIdx.x;
#pragma unroll
  for (int j = 0; j < 16; ++j) {
    int id = j * 256 + t;
    int row = id >> 5, c4 = id & 31;
    f32x4 v = *(const f32x4*)(W + (size_t)(r0 + row) * 1024 + c0 + c4 * 4);
#pragma unroll
    for (int cc = 0; cc < 4; ++cc) Tl[c4 * 4 + cc][row] = f2bf(v[cc] * scale);
  }
  __syncthreads();
  short* dst = wt + (size_t)z * 1048576;
#pragma unroll
  for (int j = 0; j < 8; ++j) {
    int id = j * 256 + t;
    int col = id >> 4, r8 = id & 15;
    *(short8*)(dst + (size_t)(c0 + col) * 1024 + r0 + r8 * 8) =
        *(const short8*)&Tl[col][r8 * 8];
  }
}

// ---------------------------------------------------------------------------
// QKV (256^2 ring): z=0 Q (scaled) [16384][1024]; z=1 K; z=2 V^T [4][1024][4096]
// ---------------------------------------------------------------------------
__global__ __launch_bounds__(512, 2)
void qkv_gemm(const short* __restrict__ xb, const short* __restrict__ wt,
              short* __restrict__ q, short* __restrict__ k,
              short* __restrict__ vt) {
  extern __shared__ short lds[];
  const int z = blockIdx.z;
  const int n0 = blockIdx.x * 256, m0 = blockIdx.y * 256;
  const int t = threadIdx.x;
  f32x4 acc[8][4] = {};
  gemm256_ring(xb + (size_t)m0 * 1024, 1024,
               wt + (size_t)z * 1048576 + (size_t)n0 * 1024, 1024, 1024,
               lds, t, acc);
  const int w = t >> 6, lane = t & 63;
  const int lr = lane & 15, lk = lane >> 4;
  const int wm = w >> 2, wn = w & 3;
#pragma unroll
  for (int mt = 0; mt < 8; ++mt) {
#pragma unroll
    for (int nt = 0; nt < 4; ++nt) {
      int col = n0 + wn * 64 + nt * 16 + lr;
      int rbase = m0 + wm * 128 + mt * 16 + lk * 4;
      if (z == 2) {
        int bb = rbase >> 12, s = rbase & 4095;
        short4v h = { f2bf(acc[mt][nt][0]), f2bf(acc[mt][nt][1]),
                      f2bf(acc[mt][nt][2]), f2bf(acc[mt][nt][3]) };
        *(short4v*)(vt + ((size_t)bb * 1024 + col) * 4096 + s) = h;
      } else {
        short* dst = (z == 0) ? q : k;
#pragma unroll
        for (int i = 0; i < 4; ++i)
          dst[(size_t)(rbase + i) * 1024 + col] = f2bf(acc[mt][nt][i]);
      }
    }
  }
}

// ---------------------------------------------------------------------------
// S pass (256^2 ring): lower-triangle 256-tiles. E = exp(S) (|S| small),
// P bf16 [b][4096][4096]; row partial sums -> lpart[tj*4+wn][16384].
// ---------------------------------------------------------------------------
__global__ __launch_bounds__(512, 2)
void s_gemm(const short* __restrict__ q, const short* __restrict__ k,
            short* __restrict__ P, float* __restrict__ lpart) {
  extern __shared__ short lds[];
  const int bid = blockIdx.x;
  const int b = bid & 3, tt = bid >> 2;
  int ti = (int)((sqrtf(8.f * tt + 1.f) - 1.f) * 0.5f);
  while ((ti + 1) * (ti + 2) / 2 <= tt) ++ti;
  while (ti * (ti + 1) / 2 > tt) --ti;
  const int tj = tt - ti * (ti + 1) / 2;
  const int t = threadIdx.x;
  f32x4 acc[8][4] = {};
  gemm256_ring(q + ((size_t)(b * 4096 + ti * 256)) * 1024, 1024,
               k + ((size_t)(b * 4096 + tj * 256)) * 1024, 1024, 1024,
               lds, t, acc);
  const int w = t >> 6, lane = t & 63;
  const int lr = lane & 15, lk = lane >> 4;
  const int wm = w >> 2, wn = w & 3;
  const bool diag = (ti == tj);
#pragma unroll
  for (int mt = 0; mt < 8; ++mt) {
#pragma unroll
    for (int i = 0; i < 4; ++i) {
      const int rl = wm * 128 + mt * 16 + lk * 4 + i;
      size_t prow = ((size_t)(b * 4096 + ti * 256 + rl)) * 4096 + tj * 256;
      float rs = 0.f;
#pragma unroll
      for (int nt = 0; nt < 4; ++nt) {
        const int cl = wn * 64 + nt * 16 + lr;
        float e = (!diag || cl <= rl) ? __expf(acc[mt][nt][i]) : 0.f;
        short pb = f2bf(e);
        P[prow + cl] = pb;
        rs += bf2f(pb);
      }
      rs += __shfl_xor(rs, 1);
      rs += __shfl_xor(rs, 2);
      rs += __shfl_xor(rs, 4);
      rs += __shfl_xor(rs, 8);
      if (lr == 0)
        lpart[((size_t)(tj * 4 + wn)) * 16384 + b * 4096 + ti * 256 + rl] = rs;
    }
  }
}

// ---------------------------------------------------------------------------
// l[row] = sum over valid tj slices (fixed order -> deterministic)
// ---------------------------------------------------------------------------
__global__ __launch_bounds__(256)
void l_reduce(const float* __restrict__ lpart, float* __restrict__ lsum) {
  int idx = blockIdx.x * 256 + threadIdx.x;     // 16384
  int qq = idx & 4095;
  int ti = qq >> 8;                             // 256-tile index
  float s = 0.f;
  for (int tj = 0; tj <= ti; ++tj) {
#pragma unroll
    for (int e = 0; e < 4; ++e)
      s += lpart[(size_t)(tj * 4 + e) * 16384 + idx];
  }
  lsum[idx] = s;
}

// ---------------------------------------------------------------------------
// PV pass (128^2 core): O[128q x 128d], kext=(qt+1)*128, /l -> f32 out.
// Descending-qt block order for load balance.
// ---------------------------------------------------------------------------
__global__ __launch_bounds__(256)
void pv_gemm(const short* __restrict__ P, const short* __restrict__ vt,
             const float* __restrict__ lsum, float* __restrict__ out) {
  __shared__ short Alds[128 * 32], Blds[128 * 32];
  const int bid = blockIdx.x;
  const int b = bid & 3;
  const int r = bid >> 2;
  const int dt = r & 7;
  const int qt = 31 - (r >> 3);
  const int t = threadIdx.x, w = t >> 6, lane = t & 63;
  f32x4 acc[4][4] = {};
  gemm_tile128(P + ((size_t)(b * 4096 + qt * 128)) * 4096, 4096,
               vt + ((size_t)(b * 1024 + dt * 128)) * 4096, 4096,
               (qt + 1) * 128, Alds, Blds, w, lane, acc);
  const int lr = lane & 15, lk = lane >> 4;
  const int wr = (w >> 1) * 64, wc = (w & 1) * 64;
#pragma unroll
  for (int mt = 0; mt < 4; ++mt) {
#pragma unroll
    for (int i = 0; i < 4; ++i) {
      int rl = wr + mt * 16 + lk * 4 + i;
      int grow = b * 4096 + qt * 128 + rl;
      float inv = 1.0f / lsum[grow];
#pragma unroll
      for (int nt = 0; nt < 4; ++nt) {
        int cl = wc + nt * 16 + lr;
        out[(size_t)grow * 1024 + dt * 128 + cl] = acc[mt][nt][i] * inv;
      }
    }
  }
}

// ---------------------------------------------------------------------------
extern "C" void kernel_launch(void* const* d_in, const int* in_sizes, int n_in,
                              void* d_out, int out_size, void* d_ws, size_t ws_size,
                              hipStream_t stream) {
  (void)in_sizes; (void)n_in; (void)out_size; (void)ws_size;
  const float* x  = (const float*)d_in[0];
  const float* Wq = (const float*)d_in[1];
  const float* Wk = (const float*)d_in[2];
  const float* Wv = (const float*)d_in[3];
  float* out = (float*)d_out;

  short* q_ws  = (short*)d_ws;                       // 32MB
  short* k_ws  = q_ws + (size_t)16777216;            // 32MB
  short* vt_ws = k_ws + (size_t)16777216;            // 32MB
  short* P     = vt_ws + (size_t)16777216;           // 128MB
  short* xb    = P;                                  // alias: consumed before P written
  float* lpart = (float*)(P + (size_t)67108864);     // 64*16384 f32 (4MB)
  float* lsum  = lpart + (size_t)64 * 16384;         // 16384 f32
  short* wt    = (short*)(lsum + 16384);             // 6MB

  const int gemm_lds = 131072;  // 128 KiB: 4-slot ring
  hipFuncSetAttribute((const void*)qkv_gemm,
                      hipFuncAttributeMaxDynamicSharedMemorySize, gemm_lds);
  hipFuncSetAttribute((const void*)s_gemm,
                      hipFuncAttributeMaxDynamicSharedMemorySize, gemm_lds);

  cvt_x<<<dim3(8192), 256, 0, stream>>>(x, xb);
  cvt_w<<<dim3(8, 8, 3), 256, 0, stream>>>(Wq, Wk, Wv, wt);
  qkv_gemm<<<dim3(4, 64, 3), 512, gemm_lds, stream>>>(xb, wt, q_ws, k_ws, vt_ws);
  s_gemm<<<dim3(544), 512, gemm_lds, stream>>>(q_ws, k_ws, P, lpart);
  l_reduce<<<dim3(64), 256, 0, stream>>>(lpart, lsum);
  pv_gemm<<<dim3(1024), 256, 0, stream>>>(P, vt_ws, lsum, out);
}

// Round 7
// 337.569 us; speedup vs baseline: 1.0468x; 1.0468x over previous
//
#include <hip/hip_runtime.h>
#include <hip/hip_bf16.h>
#include <stdint.h>

typedef short short8 __attribute__((ext_vector_type(8)));
typedef short short4v __attribute__((ext_vector_type(4)));
typedef float f32x4 __attribute__((ext_vector_type(4)));

static __device__ __forceinline__ short f2bf(float f) {
  union { float f; uint32_t u; } v; v.f = f;
  uint32_t r = (v.u + 0x7fffu + ((v.u >> 16) & 1u)) >> 16;
  return (short)(uint16_t)r;
}
static __device__ __forceinline__ float bf2f(short h) {
  union { uint32_t u; float f; } v; v.u = ((uint32_t)(uint16_t)h) << 16;
  return v.f;
}

#define MFMA(a, b, c) __builtin_amdgcn_mfma_f32_16x16x32_bf16((a), (b), (c), 0, 0, 0)

static __device__ __forceinline__ void gload16(const short* g, short* l) {
  __builtin_amdgcn_global_load_lds(
      (const __attribute__((address_space(1))) void*)g,
      (__attribute__((address_space(3))) void*)l, 16, 0, 0);
}

// ===========================================================================
// 256x256 GEMM, BK=64, faithful m201-style 4-phase/K-tile schedule.
// 512 threads = 8 waves (wm 0-1 x wn 0-3), wave tile 128x64, acc[8][4].
// LDS 128 KiB: A bufs [0,16K),[16K,32K); B bufs [32K,48K),[48K,64K) shorts.
// Phase p = (mh=p>>1, kh=p&1): ds_read 4 A b128 (+4 B b128 at p0/p1, B held
// in regs for p2/p3); 16 MFMA. Staging of tile t+1 spread 2 gloads/phase in
// consumption order: p0 B-q0,q2; p1 B-q1,q3; p2 A-q0,q2; p3 A-q1,q3 (quarter
// = 64 rows x 64 k = 8KB = 1 gload/wave-slice; dest buffer was freed at end
// of tile t-1 -> no race). Counted waits, never 0 in-loop: end-p1 vmcnt(4)
// (covers this tile's A-q1,q3), end-p3 vmcnt(2) (covers next p0's B + A-q0,2).
// LDS chunk swizzle c ^ (row&7) (measured 0 conflicts); global src
// pre-swizzled, gload dest linear. acc C/D: col=lane&15, row=(lane>>4)*4+i.
// ===========================================================================
static __device__ __forceinline__ void gemm256_m201(
    const short* __restrict__ Ag, int lda,
    const short* __restrict__ Bg, int ldb, int kext,
    short* lds, int t, f32x4 (&acc)[8][4])
{
  const int w = t >> 6, lane = t & 63;
  const int lr = lane & 15, lk = lane >> 4;
  const int wm = w >> 2, wn = w & 3;
  const int nk = kext >> 6;

  short* const Ab0 = lds;
  short* const Ab1 = lds + 16384;
  short* const Bb0 = lds + 32768;
  short* const Bb1 = lds + 49152;

  // staging: thread t covers 16B slot t of each 8KB quarter
  const int qr = t >> 3;
  const int qc = (t & 7) ^ (qr & 7);
  const short* Asrc = Ag + (size_t)qr * lda + qc * 8;
  const short* Bsrc = Bg + (size_t)qr * ldb + qc * 8;

#define STAGE_A(tile, q) gload16(Asrc + (size_t)(q) * 64 * lda + (tile) * 64, \
    (((tile) & 1) ? Ab1 : Ab0) + (q) * 4096 + w * 512)
#define STAGE_B(tile, q) gload16(Bsrc + (size_t)(q) * 64 * ldb + (tile) * 64, \
    (((tile) & 1) ? Bb1 : Bb0) + (q) * 4096 + w * 512)

  // ds_read chunk offsets (row&7 == lr&7 for all fragment rows)
  const int chq0 = ((lk) ^ (lr & 7)) * 8;
  const int chq1 = ((4 + lk) ^ (lr & 7)) * 8;
  const int arow0 = (wm * 128 + lr) * 64;        // + mt*1024 (+ mh*4096)
  const int brow0 = (wn * 64 + lr) * 64;         // + nt*1024

  // prologue: tile 0 in consumption-priority order, then retire first 6
  STAGE_B(0, 0); STAGE_B(0, 2); STAGE_B(0, 1); STAGE_B(0, 3);
  STAGE_A(0, 0); STAGE_A(0, 2); STAGE_A(0, 1); STAGE_A(0, 3);
  asm volatile("s_waitcnt vmcnt(2)" ::: "memory");
  __builtin_amdgcn_s_barrier();

  for (int tt = 0; tt < nk; ++tt) {
    const short* Ac = (tt & 1) ? Ab1 : Ab0;
    const short* Bc = (tt & 1) ? Bb1 : Bb0;
    const int nx = tt + 1;
    const bool st = nx < nk;
    short8 b0[4], b1[4], af[4];

    // ---- phase 0: mh=0, kh=0 ----
#pragma unroll
    for (int mt = 0; mt < 4; ++mt)
      af[mt] = *(const short8*)&Ac[arow0 + mt * 1024 + chq0];
#pragma unroll
    for (int nt = 0; nt < 4; ++nt)
      b0[nt] = *(const short8*)&Bc[brow0 + nt * 1024 + chq0];
    if (st) { STAGE_B(nx, 0); STAGE_B(nx, 2); }
    __builtin_amdgcn_s_barrier();
    asm volatile("s_waitcnt lgkmcnt(0)" ::: "memory");
    __builtin_amdgcn_sched_barrier(0);
    __builtin_amdgcn_s_setprio(1);
#pragma unroll
    for (int mt = 0; mt < 4; ++mt)
#pragma unroll
      for (int nt = 0; nt < 4; ++nt)
        acc[mt][nt] = MFMA(af[mt], b0[nt], acc[mt][nt]);
    __builtin_amdgcn_s_setprio(0);
    __builtin_amdgcn_s_barrier();

    // ---- phase 1: mh=0, kh=1 ----
#pragma unroll
    for (int mt = 0; mt < 4; ++mt)
      af[mt] = *(const short8*)&Ac[arow0 + mt * 1024 + chq1];
#pragma unroll
    for (int nt = 0; nt < 4; ++nt)
      b1[nt] = *(const short8*)&Bc[brow0 + nt * 1024 + chq1];
    if (st) { STAGE_B(nx, 1); STAGE_B(nx, 3); }
    __builtin_amdgcn_s_barrier();
    asm volatile("s_waitcnt lgkmcnt(0)" ::: "memory");
    __builtin_amdgcn_sched_barrier(0);
    __builtin_amdgcn_s_setprio(1);
#pragma unroll
    for (int mt = 0; mt < 4; ++mt)
#pragma unroll
      for (int nt = 0; nt < 4; ++nt)
        acc[mt][nt] = MFMA(af[mt], b1[nt], acc[mt][nt]);
    __builtin_amdgcn_s_setprio(0);
    if (st) { asm volatile("s_waitcnt vmcnt(4)" ::: "memory"); }
    else    { asm volatile("s_waitcnt vmcnt(0)" ::: "memory"); }
    __builtin_amdgcn_s_barrier();

    // ---- phase 2: mh=1, kh=0 (B reused from regs) ----
#pragma unroll
    for (int mt = 0; mt < 4; ++mt)
      af[mt] = *(const short8*)&Ac[arow0 + 4096 + mt * 1024 + chq0];
    if (st) { STAGE_A(nx, 0); STAGE_A(nx, 2); }
    __builtin_amdgcn_s_barrier();
    asm volatile("s_waitcnt lgkmcnt(0)" ::: "memory");
    __builtin_amdgcn_sched_barrier(0);
    __builtin_amdgcn_s_setprio(1);
#pragma unroll
    for (int mt = 0; mt < 4; ++mt)
#pragma unroll
      for (int nt = 0; nt < 4; ++nt)
        acc[4 + mt][nt] = MFMA(af[mt], b0[nt], acc[4 + mt][nt]);
    __builtin_amdgcn_s_setprio(0);
    __builtin_amdgcn_s_barrier();

    // ---- phase 3: mh=1, kh=1 ----
#pragma unroll
    for (int mt = 0; mt < 4; ++mt)
      af[mt] = *(const short8*)&Ac[arow0 + 4096 + mt * 1024 + chq1];
    if (st) { STAGE_A(nx, 1); STAGE_A(nx, 3); }
    __builtin_amdgcn_s_barrier();
    asm volatile("s_waitcnt lgkmcnt(0)" ::: "memory");
    __builtin_amdgcn_sched_barrier(0);
    __builtin_amdgcn_s_setprio(1);
#pragma unroll
    for (int mt = 0; mt < 4; ++mt)
#pragma unroll
      for (int nt = 0; nt < 4; ++nt)
        acc[4 + mt][nt] = MFMA(af[mt], b1[nt], acc[4 + mt][nt]);
    __builtin_amdgcn_s_setprio(0);
    if (st) { asm volatile("s_waitcnt vmcnt(2)" ::: "memory"); }
    else    { asm volatile("s_waitcnt vmcnt(0)" ::: "memory"); }
    __builtin_amdgcn_s_barrier();
  }
#undef STAGE_A
#undef STAGE_B
}

// ===========================================================================
// 128x128 2-barrier GEMM core (r3, proven) — for PV (variable K, packs well).
// ===========================================================================
static __device__ __forceinline__ void gemm_tile128(
    const short* __restrict__ Ag, int lda,
    const short* __restrict__ Bg, int ldb, int kext,
    short* Alds, short* Blds, int w, int lane, f32x4 (&acc)[4][4])
{
  const int wr = (w >> 1) * 64, wc = (w & 1) * 64;
  const int lr = lane & 15, lk = lane >> 4;

  const int c0 = w * 128 + lane;
  const int c1 = c0 + 64;
  const int r0 = c0 >> 2, cg0 = (c0 & 3) ^ ((r0 >> 1) & 3);
  const int r1 = c1 >> 2, cg1 = (c1 & 3) ^ ((r1 >> 1) & 3);
  const short* a0 = Ag + (size_t)r0 * lda + cg0 * 8;
  const short* a1 = Ag + (size_t)r1 * lda + cg1 * 8;
  const short* b0 = Bg + (size_t)r0 * ldb + cg0 * 8;
  const short* b1 = Bg + (size_t)r1 * ldb + cg1 * 8;
  short* la0 = Alds + w * 1024;
  short* la1 = la0 + 512;
  short* lb0 = Blds + w * 1024;
  short* lb1 = lb0 + 512;

  int ra[4], rb[4];
#pragma unroll
  for (int mt = 0; mt < 4; ++mt) {
    int rl = wr + mt * 16 + lr;
    ra[mt] = rl * 32 + (lk ^ ((rl >> 1) & 3)) * 8;
  }
#pragma unroll
  for (int nt = 0; nt < 4; ++nt) {
    int rl = wc + nt * 16 + lr;
    rb[nt] = rl * 32 + (lk ^ ((rl >> 1) & 3)) * 8;
  }

  for (int kk = 0; kk < kext; kk += 32) {
    if (kk) __syncthreads();
    gload16(a0 + kk, la0);
    gload16(a1 + kk, la1);
    gload16(b0 + kk, lb0);
    gload16(b1 + kk, lb1);
    __syncthreads();
    short8 af[4], bfr[4];
#pragma unroll
    for (int mt = 0; mt < 4; ++mt) af[mt] = *(const short8*)&Alds[ra[mt]];
#pragma unroll
    for (int nt = 0; nt < 4; ++nt) bfr[nt] = *(const short8*)&Blds[rb[nt]];
#pragma unroll
    for (int mt = 0; mt < 4; ++mt)
#pragma unroll
      for (int nt = 0; nt < 4; ++nt)
        acc[mt][nt] = MFMA(af[mt], bfr[nt], acc[mt][nt]);
  }
}

// ---------------------------------------------------------------------------
// x f32 -> bf16
// ---------------------------------------------------------------------------
__global__ __launch_bounds__(256)
void cvt_x(const float* __restrict__ x, short* __restrict__ xb) {
  size_t i = (size_t)blockIdx.x * 256 + threadIdx.x;
  f32x4 a = *(const f32x4*)(x + i * 8);
  f32x4 b = *(const f32x4*)(x + i * 8 + 4);
  short8 h = { f2bf(a.x), f2bf(a.y), f2bf(a.z), f2bf(a.w),
               f2bf(b.x), f2bf(b.y), f2bf(b.z), f2bf(b.w) };
  *(short8*)(xb + i * 8) = h;
}

// ---------------------------------------------------------------------------
// W f32 [din][dout] -> Wt bf16 [z][dout][din]  (z=0 folds the 1/32 scale)
// ---------------------------------------------------------------------------
__global__ __launch_bounds__(256)
void cvt_w(const float* __restrict__ Wq, const float* __restrict__ Wk,
           const float* __restrict__ Wv, short* __restrict__ wt) {
  __shared__ short Tl[128][136];
  const int z = blockIdx.z;
  const float* W = (z == 0) ? Wq : (z == 1) ? Wk : Wv;
  const float scale = (z == 0) ? 0.03125f : 1.0f;
  const int c0 = blockIdx.x * 128, r0 = blockIdx.y * 128;
  const int t = threadIdx.x;
#pragma unroll
  for (int j = 0; j < 16; ++j) {
    int id = j * 256 + t;
    int row = id >> 5, c4 = id & 31;
    f32x4 v = *(const f32x4*)(W + (size_t)(r0 + row) * 1024 + c0 + c4 * 4);
#pragma unroll
    for (int cc = 0; cc < 4; ++cc) Tl[c4 * 4 + cc][row] = f2bf(v[cc] * scale);
  }
  __syncthreads();
  short* dst = wt + (size_t)z * 1048576;
#pragma unroll
  for (int j = 0; j < 8; ++j) {
    int id = j * 256 + t;
    int col = id >> 4, r8 = id & 15;
    *(short8*)(dst + (size_t)(c0 + col) * 1024 + r0 + r8 * 8) =
        *(const short8*)&Tl[col][r8 * 8];
  }
}

// ---------------------------------------------------------------------------
// QKV (256^2 m201): z=0 Q (scaled) [16384][1024]; z=1 K; z=2 V^T [4][1024][4096]
// ---------------------------------------------------------------------------
__global__ __launch_bounds__(512, 2)
void qkv_gemm(const short* __restrict__ xb, const short* __restrict__ wt,
              short* __restrict__ q, short* __restrict__ k,
              short* __restrict__ vt) {
  extern __shared__ short lds[];
  const int z = blockIdx.z;
  const int n0 = blockIdx.x * 256, m0 = blockIdx.y * 256;
  const int t = threadIdx.x;
  f32x4 acc[8][4] = {};
  gemm256_m201(xb + (size_t)m0 * 1024, 1024,
               wt + (size_t)z * 1048576 + (size_t)n0 * 1024, 1024, 1024,
               lds, t, acc);
  const int w = t >> 6, lane = t & 63;
  const int lr = lane & 15, lk = lane >> 4;
  const int wm = w >> 2, wn = w & 3;
#pragma unroll
  for (int mt = 0; mt < 8; ++mt) {
#pragma unroll
    for (int nt = 0; nt < 4; ++nt) {
      int col = n0 + wn * 64 + nt * 16 + lr;
      int rbase = m0 + wm * 128 + mt * 16 + lk * 4;
      if (z == 2) {
        int bb = rbase >> 12, s = rbase & 4095;
        short4v h = { f2bf(acc[mt][nt][0]), f2bf(acc[mt][nt][1]),
                      f2bf(acc[mt][nt][2]), f2bf(acc[mt][nt][3]) };
        *(short4v*)(vt + ((size_t)bb * 1024 + col) * 4096 + s) = h;
      } else {
        short* dst = (z == 0) ? q : k;
#pragma unroll
        for (int i = 0; i < 4; ++i)
          dst[(size_t)(rbase + i) * 1024 + col] = f2bf(acc[mt][nt][i]);
      }
    }
  }
}

// ---------------------------------------------------------------------------
// S pass (256^2 m201): lower-triangle 256-tiles. E = exp(S) (|S| small),
// P bf16 [b][4096][4096]; row partial sums -> lpart[tj*4+wn][16384].
// ---------------------------------------------------------------------------
__global__ __launch_bounds__(512, 2)
void s_gemm(const short* __restrict__ q, const short* __restrict__ k,
            short* __restrict__ P, float* __restrict__ lpart) {
  extern __shared__ short lds[];
  const int bid = blockIdx.x;
  const int b = bid & 3, tt = bid >> 2;
  int ti = (int)((sqrtf(8.f * tt + 1.f) - 1.f) * 0.5f);
  while ((ti + 1) * (ti + 2) / 2 <= tt) ++ti;
  while (ti * (ti + 1) / 2 > tt) --ti;
  const int tj = tt - ti * (ti + 1) / 2;
  const int t = threadIdx.x;
  f32x4 acc[8][4] = {};
  gemm256_m201(q + ((size_t)(b * 4096 + ti * 256)) * 1024, 1024,
               k + ((size_t)(b * 4096 + tj * 256)) * 1024, 1024, 1024,
               lds, t, acc);
  const int w = t >> 6, lane = t & 63;
  const int lr = lane & 15, lk = lane >> 4;
  const int wm = w >> 2, wn = w & 3;
  const bool diag = (ti == tj);
#pragma unroll
  for (int mt = 0; mt < 8; ++mt) {
#pragma unroll
    for (int i = 0; i < 4; ++i) {
      const int rl = wm * 128 + mt * 16 + lk * 4 + i;
      size_t prow = ((size_t)(b * 4096 + ti * 256 + rl)) * 4096 + tj * 256;
      float rs = 0.f;
#pragma unroll
      for (int nt = 0; nt < 4; ++nt) {
        const int cl = wn * 64 + nt * 16 + lr;
        float e = (!diag || cl <= rl) ? __expf(acc[mt][nt][i]) : 0.f;
        short pb = f2bf(e);
        P[prow + cl] = pb;
        rs += bf2f(pb);
      }
      rs += __shfl_xor(rs, 1);
      rs += __shfl_xor(rs, 2);
      rs += __shfl_xor(rs, 4);
      rs += __shfl_xor(rs, 8);
      if (lr == 0)
        lpart[((size_t)(tj * 4 + wn)) * 16384 + b * 4096 + ti * 256 + rl] = rs;
    }
  }
}

// ---------------------------------------------------------------------------
// l[row] = sum over valid tj slices (fixed order -> deterministic)
// ---------------------------------------------------------------------------
__global__ __launch_bounds__(256)
void l_reduce(const float* __restrict__ lpart, float* __restrict__ lsum) {
  int idx = blockIdx.x * 256 + threadIdx.x;     // 16384
  int qq = idx & 4095;
  int ti = qq >> 8;                             // 256-tile index
  float s = 0.f;
  for (int tj = 0; tj <= ti; ++tj) {
#pragma unroll
    for (int e = 0; e < 4; ++e)
      s += lpart[(size_t)(tj * 4 + e) * 16384 + idx];
  }
  lsum[idx] = s;
}

// ---------------------------------------------------------------------------
// PV pass (128^2 core): O[128q x 128d], kext=(qt+1)*128, /l -> f32 out.
// Descending-qt block order for load balance.
// ---------------------------------------------------------------------------
__global__ __launch_bounds__(256)
void pv_gemm(const short* __restrict__ P, const short* __restrict__ vt,
             const float* __restrict__ lsum, float* __restrict__ out) {
  __shared__ short Alds[128 * 32], Blds[128 * 32];
  const int bid = blockIdx.x;
  const int b = bid & 3;
  const int r = bid >> 2;
  const int dt = r & 7;
  const int qt = 31 - (r >> 3);
  const int t = threadIdx.x, w = t >> 6, lane = t & 63;
  f32x4 acc[4][4] = {};
  gemm_tile128(P + ((size_t)(b * 4096 + qt * 128)) * 4096, 4096,
               vt + ((size_t)(b * 1024 + dt * 128)) * 4096, 4096,
               (qt + 1) * 128, Alds, Blds, w, lane, acc);
  const int lr = lane & 15, lk = lane >> 4;
  const int wr = (w >> 1) * 64, wc = (w & 1) * 64;
#pragma unroll
  for (int mt = 0; mt < 4; ++mt) {
#pragma unroll
    for (int i = 0; i < 4; ++i) {
      int rl = wr + mt * 16 + lk * 4 + i;
      int grow = b * 4096 + qt * 128 + rl;
      float inv = 1.0f / lsum[grow];
#pragma unroll
      for (int nt = 0; nt < 4; ++nt) {
        int cl = wc + nt * 16 + lr;
        out[(size_t)grow * 1024 + dt * 128 + cl] = acc[mt][nt][i] * inv;
      }
    }
  }
}

// ---------------------------------------------------------------------------
extern "C" void kernel_launch(void* const* d_in, const int* in_sizes, int n_in,
                              void* d_out, int out_size, void* d_ws, size_t ws_size,
                              hipStream_t stream) {
  (void)in_sizes; (void)n_in; (void)out_size; (void)ws_size;
  const float* x  = (const float*)d_in[0];
  const float* Wq = (const float*)d_in[1];
  const float* Wk = (const float*)d_in[2];
  const float* Wv = (const float*)d_in[3];
  float* out = (float*)d_out;

  short* q_ws  = (short*)d_ws;                       // 32MB
  short* k_ws  = q_ws + (size_t)16777216;            // 32MB
  short* vt_ws = k_ws + (size_t)16777216;            // 32MB
  short* P     = vt_ws + (size_t)16777216;           // 128MB
  short* xb    = P;                                  // alias: consumed before P written
  float* lpart = (float*)(P + (size_t)67108864);     // 64*16384 f32 (4MB)
  float* lsum  = lpart + (size_t)64 * 16384;         // 16384 f32
  short* wt    = (short*)(lsum + 16384);             // 6MB

  const int gemm_lds = 131072;  // 128 KiB: A/B double-buffered BK=64
  hipFuncSetAttribute((const void*)qkv_gemm,
                      hipFuncAttributeMaxDynamicSharedMemorySize, gemm_lds);
  hipFuncSetAttribute((const void*)s_gemm,
                      hipFuncAttributeMaxDynamicSharedMemorySize, gemm_lds);

  cvt_x<<<dim3(8192), 256, 0, stream>>>(x, xb);
  cvt_w<<<dim3(8, 8, 3), 256, 0, stream>>>(Wq, Wk, Wv, wt);
  qkv_gemm<<<dim3(4, 64, 3), 512, gemm_lds, stream>>>(xb, wt, q_ws, k_ws, vt_ws);
  s_gemm<<<dim3(544), 512, gemm_lds, stream>>>(q_ws, k_ws, P, lpart);
  l_reduce<<<dim3(64), 256, 0, stream>>>(lpart, lsum);
  pv_gemm<<<dim3(1024), 256, 0, stream>>>(P, vt_ws, lsum, out);
}